// Round 7
// baseline (145.149 us; speedup 1.0000x reference)
//
#include <hip/hip_runtime.h>
#include <math.h>

// SegmentCausalCrossAttentionFlex on MI355X (gfx950)
// B=2, LQ=4096, LK=512, Q_DIM=KV_DIM=D_ATTN=1024, H=16, HD=64, LOOKBACK=4
// R7: m201-style 8-phase GEMM core. BM=256,BN=128,BK=64; 512thr = 8 waves
// (4M x 2N), wave tile 64x64 (acc[4][4]); 3 K-tile LDS buffers (144KB);
// per phase: {2 gload_lds issue | 8 ds_read | barrier | 8-MFMA setprio
// cluster | barrier}; counted vmcnt(6) only at phases 4 and 8.

typedef unsigned short u16;
typedef __attribute__((ext_vector_type(8))) short bhalf8;   // 8 x bf16 (MFMA A/B frag)
typedef __attribute__((ext_vector_type(4))) float fvec4;    // MFMA C/D frag

#define MFMA(a, b, c) __builtin_amdgcn_mfma_f32_16x16x32_bf16((a), (b), (c), 0, 0, 0)

__device__ __forceinline__ u16 f2bf(float f) {
  unsigned u = __float_as_uint(f);
  u += 0x7fffu + ((u >> 16) & 1u);      // round-to-nearest-even
  return (u16)(u >> 16);
}
__device__ __forceinline__ float bf2f(u16 h) {
  return __uint_as_float(((unsigned)h) << 16);
}

// ---------------------------------------------------------------------------
// Fused preprocessing (unchanged from R3).
__global__ __launch_bounds__(256) void prep_kernel(
    const float* __restrict__ Wq, const float* __restrict__ Wkv,
    const float* __restrict__ Wo, u16* __restrict__ WqT,
    u16* __restrict__ WkvT, u16* __restrict__ WoT,
    const float* __restrict__ q, u16* __restrict__ qb,
    const float* __restrict__ kv, u16* __restrict__ kvb,
    float2* __restrict__ csT) {
  const int bid = blockIdx.x;
  if (bid < 4096) {
    __shared__ float tile[32][33];
    const float* W;
    u16* Wt;
    int N, t;
    if (bid < 1024)      { W = Wq;  Wt = WqT;  N = 1024; t = bid; }
    else if (bid < 3072) { W = Wkv; Wt = WkvT; N = 2048; t = bid - 1024; }
    else                 { W = Wo;  Wt = WoT;  N = 1024; t = bid - 3072; }
    const int sh = (N >> 11) + 5;               // 1024->5, 2048->6
    const int n0 = (t & ((1 << sh) - 1)) << 5;
    const int k0 = (t >> sh) << 5;
    const int tx = threadIdx.x & 31, ty = threadIdx.x >> 5;
#pragma unroll
    for (int i = 0; i < 32; i += 8)
      tile[ty + i][tx] = W[(size_t)(k0 + ty + i) * N + n0 + tx];
    __syncthreads();
#pragma unroll
    for (int i = 0; i < 32; i += 8)
      Wt[(size_t)(n0 + ty + i) * 1024 + k0 + tx] = f2bf(tile[tx][ty + i]);
    return;
  }
  const int NQ4 = 2097152, NKV4 = 262144, NR = 131072;
  const int stride = 2048 * 256;
  for (int u = (bid - 4096) * 256 + threadIdx.x; u < NQ4 + NKV4 + NR; u += stride) {
    if (u < NQ4) {
      const float4 v = ((const float4*)q)[u];
      ushort4 o;
      o.x = f2bf(v.x); o.y = f2bf(v.y); o.z = f2bf(v.z); o.w = f2bf(v.w);
      ((ushort4*)qb)[u] = o;
    } else if (u < NQ4 + NKV4) {
      const int i = u - NQ4;
      const float4 v = ((const float4*)kv)[i];
      ushort4 o;
      o.x = f2bf(v.x); o.y = f2bf(v.y); o.z = f2bf(v.z); o.w = f2bf(v.w);
      ((ushort4*)kvb)[i] = o;
    } else {
      const int i = u - NQ4 - NKV4;
      const int pos = i >> 5, j = i & 31;
      const float invf = expf(-(float)j * 0.28782313662425572f);  // ln(10000)/32
      float s, c;
      sincosf((float)pos * invf, &s, &c);
      csT[i] = make_float2(c, s);
    }
  }
}

// ---------------------------------------------------------------------------
// 8-phase 256x128 GEMM tile core. 512 thr = 8 waves (4M x 2N), wave tile
// 64x64 = acc[4][4] frags, mfma 16x16x32, BK=64, K=1024 = 16 K-tiles,
// 8 iters x 2 K-tiles. 3 LDS buffers: A 256x64 (32KB), B 128x64 (16KB).
// Chunk swizzle: LDS chunk (row, s) holds global 16B-chunk g = s ^ (row&7);
// read side XORs identically (transparent; k-order canonical).
// Per phase: issue 2 gload_lds; 8 ds_read_b128 (quadrant frags); barrier;
// lgkmcnt (compiler); setprio(1); 8 MFMA; setprio(0); barrier.
// vmcnt(6) at phases 4/8: outstanding = 12 (2 staged tiles), wait->6 means
// the older staged tile (the one needed next) landed.
// Hazards: stage t+2 -> buf[(t+2)%3] (last read 2 half-iters ago);
// stage t+3 -> buf[t%3], issued in phases 5-8 after phase-4 reads complete.
__device__ __forceinline__ void gemm_core_8ph(
    const u16* __restrict__ A, const u16* __restrict__ Bt,
    int m0, int n0, fvec4 acc[4][4], u16* As, u16* Bs) {
  const int tid = threadIdx.x;
  const int lane = tid & 63;
  const int wv = tid >> 6, wm = wv >> 1, wn = wv & 1;

  // ---- staging addresses (per K-tile: A 4 chunks/thread, B 2) ----
  const u16* aglb[4];
  int aldst[4];
#pragma unroll
  for (int j = 0; j < 4; ++j) {
    const int cidx = tid + j * 512;             // 0..2047
    const int row = cidx >> 3, g = (cidx & 7) ^ (row & 7);
    aglb[j] = A + (size_t)(m0 + row) * 1024 + g * 8;
    aldst[j] = cidx * 8;
  }
  const u16* bglb[2];
  int bldst[2];
#pragma unroll
  for (int j = 0; j < 2; ++j) {
    const int cidx = tid + j * 512;             // 0..1023
    const int row = cidx >> 3, g = (cidx & 7) ^ (row & 7);
    bglb[j] = Bt + (size_t)(n0 + row) * 1024 + g * 8;
    bldst[j] = cidx * 8;
  }

#define LD_A(buf, kk, j)                                                     \
  __builtin_amdgcn_global_load_lds(                                          \
      (__attribute__((address_space(1))) void*)(aglb[j] + (kk)),             \
      (__attribute__((address_space(3))) void*)(As + (buf) * 16384 + aldst[j]), 16, 0, 0)
#define LD_B(buf, kk, j)                                                     \
  __builtin_amdgcn_global_load_lds(                                          \
      (__attribute__((address_space(1))) void*)(bglb[j] + (kk)),             \
      (__attribute__((address_space(3))) void*)(Bs + (buf) * 8192 + bldst[j]), 16, 0, 0)

  // ---- fragment read offsets (u16 units) ----
  const int c = lane >> 4;
  const int sl0 = ((c) ^ (lane & 7)) * 8;        // ksub 0 chunk slot
  const int sl1 = ((c + 4) ^ (lane & 7)) * 8;    // ksub 1
  const int rba = (wm * 64 + (lane & 15)) * 64;  // A row base
  const int rbb = (wn * 64 + (lane & 15)) * 64;  // B row base

#define PH(bufi, QM, QN, STAGE, TAIL)                                        \
  do {                                                                       \
    STAGE;                                                                   \
    const u16* Ab = As + (bufi) * 16384 + rba;                               \
    const u16* Bb = Bs + (bufi) * 8192 + rbb;                                \
    const bhalf8 a00 = *(const bhalf8*)(Ab + (QM * 2) * 1024 + sl0);         \
    const bhalf8 a01 = *(const bhalf8*)(Ab + (QM * 2) * 1024 + sl1);         \
    const bhalf8 a10 = *(const bhalf8*)(Ab + (QM * 2 + 1) * 1024 + sl0);     \
    const bhalf8 a11 = *(const bhalf8*)(Ab + (QM * 2 + 1) * 1024 + sl1);     \
    const bhalf8 b00 = *(const bhalf8*)(Bb + (QN * 2) * 1024 + sl0);         \
    const bhalf8 b01 = *(const bhalf8*)(Bb + (QN * 2) * 1024 + sl1);         \
    const bhalf8 b10 = *(const bhalf8*)(Bb + (QN * 2 + 1) * 1024 + sl0);     \
    const bhalf8 b11 = *(const bhalf8*)(Bb + (QN * 2 + 1) * 1024 + sl1);     \
    __builtin_amdgcn_s_barrier();                                            \
    __builtin_amdgcn_s_setprio(1);                                           \
    acc[QM * 2][QN * 2]         = MFMA(a00, b00, acc[QM * 2][QN * 2]);       \
    acc[QM * 2][QN * 2]         = MFMA(a01, b01, acc[QM * 2][QN * 2]);       \
    acc[QM * 2][QN * 2 + 1]     = MFMA(a00, b10, acc[QM * 2][QN * 2 + 1]);   \
    acc[QM * 2][QN * 2 + 1]     = MFMA(a01, b11, acc[QM * 2][QN * 2 + 1]);   \
    acc[QM * 2 + 1][QN * 2]     = MFMA(a10, b00, acc[QM * 2 + 1][QN * 2]);   \
    acc[QM * 2 + 1][QN * 2]     = MFMA(a11, b01, acc[QM * 2 + 1][QN * 2]);   \
    acc[QM * 2 + 1][QN * 2 + 1] = MFMA(a10, b10, acc[QM * 2 + 1][QN * 2 + 1]);\
    acc[QM * 2 + 1][QN * 2 + 1] = MFMA(a11, b11, acc[QM * 2 + 1][QN * 2 + 1]);\
    __builtin_amdgcn_s_setprio(0);                                           \
    TAIL;                                                                    \
  } while (0)

#define BAR __builtin_amdgcn_s_barrier()
#define VMTAIL(st)                                                           \
  do {                                                                       \
    if (st) asm volatile("s_waitcnt vmcnt(6)" ::: "memory");                 \
    else    asm volatile("s_waitcnt vmcnt(0)" ::: "memory");                 \
    __builtin_amdgcn_s_barrier();                                            \
  } while (0)

  // ---- prologue: stage K-tiles 0 (buf0) and 1 (buf1) ----
#pragma unroll
  for (int j = 0; j < 4; ++j) LD_A(0, 0, j);
#pragma unroll
  for (int j = 0; j < 2; ++j) LD_B(0, 0, j);
#pragma unroll
  for (int j = 0; j < 4; ++j) LD_A(1, 64, j);
#pragma unroll
  for (int j = 0; j < 2; ++j) LD_B(1, 64, j);
  asm volatile("s_waitcnt vmcnt(6)" ::: "memory");   // tile 0 landed
  __builtin_amdgcn_s_barrier();

  int b0 = 0;
#pragma unroll 1
  for (int it = 0; it < 8; ++it) {
    const int b1 = (b0 == 2) ? 0 : b0 + 1;
    const int b2 = (b1 == 2) ? 0 : b1 + 1;
    const int kk2 = it * 128 + 128;   // K-tile 2it+2 -> buf b2
    const int kk3 = it * 128 + 192;   // K-tile 2it+3 -> buf b0
    const bool st = it < 7;
    // half 1: compute K-tile 2it (buf b0)
    PH(b0, 0, 0, if (st) { LD_A(b2, kk2, 0); LD_A(b2, kk2, 1); }, BAR);
    PH(b0, 0, 1, if (st) { LD_A(b2, kk2, 2); LD_A(b2, kk2, 3); }, BAR);
    PH(b0, 1, 0, if (st) { LD_B(b2, kk2, 0); LD_B(b2, kk2, 1); }, BAR);
    PH(b0, 1, 1, (void)0, VMTAIL(st));
    // half 2: compute K-tile 2it+1 (buf b1)
    PH(b1, 0, 0, if (st) { LD_A(b0, kk3, 0); LD_A(b0, kk3, 1); }, BAR);
    PH(b1, 0, 1, if (st) { LD_A(b0, kk3, 2); LD_A(b0, kk3, 3); }, BAR);
    PH(b1, 1, 0, if (st) { LD_B(b0, kk3, 0); LD_B(b0, kk3, 1); }, BAR);
    PH(b1, 1, 1, (void)0, VMTAIL(st));
    b0 = b2;
  }
#undef PH
#undef BAR
#undef VMTAIL
#undef LD_A
#undef LD_B
}

#define GEMM_PROLOGUE()                                              \
  __shared__ __align__(16) u16 As[3 * 256 * 64];                     \
  __shared__ __align__(16) u16 Bs[3 * 128 * 64];                     \
  fvec4 acc[4][4];                                                   \
  _Pragma("unroll") for (int i = 0; i < 4; ++i)                      \
      _Pragma("unroll") for (int j = 0; j < 4; ++j)                  \
          acc[i][j] = (fvec4){0.f, 0.f, 0.f, 0.f};

// ---------------------------------------------------------------------------
// Fused GEMM1+GEMM2, 320 wgs x 512 thr (8 XCD chunks of 40).
// role swz<256:  qh = bf16( RoPE(q @ Wq) * 0.125 )  M=8192 N=1024 (32x8)
// role swz>=256: kvl = kv @ Wkv (4x16); cols<1024 -> kh (RoPE), else vh
__global__ __launch_bounds__(512) void gemm12_kernel(
    const u16* __restrict__ qA, const u16* __restrict__ WqT,
    const u16* __restrict__ kvA, const u16* __restrict__ WkvT,
    u16* __restrict__ qh, u16* __restrict__ kh, u16* __restrict__ vh,
    const int* __restrict__ qpos, const int* __restrict__ kpos,
    const float2* __restrict__ csT) {
  GEMM_PROLOGUE();
  const int swz = ((blockIdx.x & 7) * 40) + (blockIdx.x >> 3);  // bijective, 320=8*40
  const int lane = threadIdx.x & 63;
  const int wv = threadIdx.x >> 6, wm = wv >> 1, wn = wv & 1;

  const u16 *A, *Bt;
  int m0, n0;
  if (swz < 256) {
    A = qA; Bt = WqT;
    m0 = (swz >> 3) * 256; n0 = (swz & 7) * 128;
  } else {
    const int t = swz - 256;                       // 0..63
    A = kvA; Bt = WkvT;
    m0 = (t >> 4) * 256; n0 = (t & 15) * 128;
  }
  gemm_core_8ph(A, Bt, m0, n0, acc, As, Bs);

  if (swz < 256) {
#pragma unroll
    for (int mi = 0; mi < 4; ++mi) {
#pragma unroll
      for (int r = 0; r < 4; ++r) {
        const int rowg = m0 + wm * 64 + mi * 16 + (lane >> 4) * 4 + r;
        int pos = qpos[rowg];
        pos = pos < 0 ? 0 : (pos > 4095 ? 4095 : pos);
#pragma unroll
        for (int ni = 0; ni < 2; ++ni) {
          const int j = ni * 16 + (lane & 15);
          const float2 cs = csT[pos * 32 + j];
          const float x1 = acc[mi][ni][r], x2 = acc[mi][ni + 2][r];
          const int colg = n0 + wn * 64 + ni * 16 + (lane & 15);
          qh[(size_t)rowg * 1024 + colg]      = f2bf((x1 * cs.x - x2 * cs.y) * 0.125f);
          qh[(size_t)rowg * 1024 + colg + 32] = f2bf((x2 * cs.x + x1 * cs.y) * 0.125f);
        }
      }
    }
  } else {
    const bool isK = (n0 + wn * 64) < 1024;
#pragma unroll
    for (int mi = 0; mi < 4; ++mi) {
#pragma unroll
      for (int r = 0; r < 4; ++r) {
        const int rowg = m0 + wm * 64 + mi * 16 + (lane >> 4) * 4 + r;  // 0..1023
        if (isK) {
          int pos = kpos[rowg & 511];
          pos = pos < 0 ? 0 : (pos > 4095 ? 4095 : pos);
#pragma unroll
          for (int ni = 0; ni < 2; ++ni) {
            const int j = ni * 16 + (lane & 15);
            const float2 cs = csT[pos * 32 + j];
            const float x1 = acc[mi][ni][r], x2 = acc[mi][ni + 2][r];
            const int colg = n0 + wn * 64 + ni * 16 + (lane & 15);
            kh[(size_t)rowg * 1024 + colg]      = f2bf(x1 * cs.x - x2 * cs.y);
            kh[(size_t)rowg * 1024 + colg + 32] = f2bf(x2 * cs.x + x1 * cs.y);
          }
        } else {
#pragma unroll
          for (int ni = 0; ni < 4; ++ni) {
            const int colg = n0 + wn * 64 + ni * 16 + (lane & 15);
            vh[(size_t)rowg * 1024 + colg - 1024] = f2bf(acc[mi][ni][r]);
          }
        }
      }
    }
  }
}

// ---------------------------------------------------------------------------
// GEMM3: out_f32 = ctx @ Wo   M=8192 N=1024, 256 wgs x 512 thr (full chip)
__global__ __launch_bounds__(512) void gemm_out_kernel(
    const u16* __restrict__ A, const u16* __restrict__ Bt,
    float* __restrict__ out) {
  GEMM_PROLOGUE();
  const int wg = ((blockIdx.x & 7) << 5) + (blockIdx.x >> 3);  // XCD swizzle, 256=8*32
  const int m0 = (wg >> 3) * 256, n0 = (wg & 7) * 128;
  gemm_core_8ph(A, Bt, m0, n0, acc, As, Bs);
  const int lane = threadIdx.x & 63;
  const int wv = threadIdx.x >> 6, wm = wv >> 1, wn = wv & 1;
#pragma unroll
  for (int mi = 0; mi < 4; ++mi) {
#pragma unroll
    for (int r = 0; r < 4; ++r) {
      const int rowg = m0 + wm * 64 + mi * 16 + (lane >> 4) * 4 + r;
#pragma unroll
      for (int ni = 0; ni < 4; ++ni) {
        const int colg = n0 + wn * 64 + ni * 16 + (lane & 15);
        out[(size_t)rowg * 1024 + colg] = acc[mi][ni][r];
      }
    }
  }
}

// ---------------------------------------------------------------------------
// Sparse attention (unchanged): k in [max(seg-4,0), seg] (<=5 keys).
__global__ __launch_bounds__(256) void attn_kernel(
    const u16* __restrict__ qh, const u16* __restrict__ kh,
    const u16* __restrict__ vh, const int* __restrict__ seg_id,
    u16* __restrict__ ctx) {
  const int lane = threadIdx.x & 63;
  const int row = (blockIdx.x * 256 + threadIdx.x) >> 6;   // 0..8191
  const int b = row >> 12;
  const int sg = seg_id[row];
  const int kmin = sg > 4 ? sg - 4 : 0;

  const u16* qp = qh + (size_t)row * 1024 + lane * 16;
  const bhalf8 qa = *(const bhalf8*)qp;
  const bhalf8 qb = *(const bhalf8*)(qp + 8);
  float qv[16];
#pragma unroll
  for (int e = 0; e < 8; ++e) {
    qv[e] = bf2f((u16)qa[e]);
    qv[8 + e] = bf2f((u16)qb[e]);
  }

  float sc[5];
  float mx = -3.0e38f;
#pragma unroll
  for (int t = 0; t < 5; ++t) {
    const int k = kmin + t;                      // always in [0,511]
    const u16* kp = kh + (size_t)((b << 9) + k) * 1024 + lane * 16;
    const bhalf8 ka = *(const bhalf8*)kp;
    const bhalf8 kb = *(const bhalf8*)(kp + 8);
    float d = 0.f;
#pragma unroll
    for (int e = 0; e < 8; ++e)
      d += qv[e] * bf2f((u16)ka[e]) + qv[8 + e] * bf2f((u16)kb[e]);
    d += __shfl_xor(d, 1);
    d += __shfl_xor(d, 2);                       // sum over 4 lanes of this head
    sc[t] = (k <= sg) ? d : -3.0e38f;
    mx = fmaxf(mx, sc[t]);
  }

  float den = 0.f;
  float o[16];
#pragma unroll
  for (int e = 0; e < 16; ++e) o[e] = 0.f;
#pragma unroll
  for (int t = 0; t < 5; ++t) {
    const float p = __expf(sc[t] - mx);          // masked -> exp(-huge) = 0
    den += p;
    const int k = kmin + t;
    const u16* vp = vh + (size_t)((b << 9) + k) * 1024 + lane * 16;
    const bhalf8 va = *(const bhalf8*)vp;
    const bhalf8 vb = *(const bhalf8*)(vp + 8);
#pragma unroll
    for (int e = 0; e < 8; ++e) {
      o[e] += p * bf2f((u16)va[e]);
      o[8 + e] += p * bf2f((u16)vb[e]);
    }
  }
  const float inv = 1.f / den;
  bhalf8 oa, ob;
#pragma unroll
  for (int e = 0; e < 8; ++e) {
    oa[e] = (short)f2bf(o[e] * inv);
    ob[e] = (short)f2bf(o[8 + e] * inv);
  }
  u16* cp = ctx + (size_t)row * 1024 + lane * 16;
  *(bhalf8*)cp = oa;
  *(bhalf8*)(cp + 8) = ob;
}

// ---------------------------------------------------------------------------
extern "C" void kernel_launch(void* const* d_in, const int* in_sizes, int n_in,
                              void* d_out, int out_size, void* d_ws, size_t ws_size,
                              hipStream_t stream) {
  const float* q   = (const float*)d_in[0];
  const float* kv  = (const float*)d_in[1];
  const int* qpos  = (const int*)d_in[2];
  const int* kpos  = (const int*)d_in[3];
  const int* seg   = (const int*)d_in[4];
  const float* Wq  = (const float*)d_in[5];
  const float* Wkv = (const float*)d_in[6];
  const float* Wo  = (const float*)d_in[7];
  float* out = (float*)d_out;

  // workspace carve-up (~66 MB total)
  char* w = (char*)d_ws;
  u16* qb    = (u16*)w; w += (size_t)8192 * 1024 * 2;
  u16* kvb   = (u16*)w; w += (size_t)1024 * 1024 * 2;
  u16* WqT   = (u16*)w; w += (size_t)1024 * 1024 * 2;
  u16* WkvT  = (u16*)w; w += (size_t)2048 * 1024 * 2;
  u16* WoT   = (u16*)w; w += (size_t)1024 * 1024 * 2;
  u16* qhB   = (u16*)w; w += (size_t)8192 * 1024 * 2;
  u16* khB   = (u16*)w; w += (size_t)1024 * 1024 * 2;
  u16* vhB   = (u16*)w; w += (size_t)1024 * 1024 * 2;
  u16* ctxB  = (u16*)w; w += (size_t)8192 * 1024 * 2;
  float2* csT = (float2*)w; w += (size_t)4096 * 32 * 8;

  prep_kernel<<<6144, 256, 0, stream>>>(Wq, Wkv, Wo, WqT, WkvT, WoT,
                                        q, qb, kv, kvb, csT);
  gemm12_kernel<<<320, 512, 0, stream>>>(qb, WqT, kvb, WkvT,
                                         qhB, khB, vhB, qpos, kpos, csT);
  attn_kernel<<<2048, 256, 0, stream>>>(qhB, khB, vhB, seg, ctxB);
  gemm_out_kernel<<<256, 512, 0, stream>>>(ctxB, WoT, out);
}

// Round 8
// 93.101 us; speedup vs baseline: 1.5590x; 1.5590x over previous
//
#include <hip/hip_runtime.h>
#include <math.h>

// SegmentCausalCrossAttentionFlex on MI355X (gfx950)
// B=2, LQ=4096, LK=512, Q_DIM=KV_DIM=D_ATTN=1024, H=16, HD=64, LOOKBACK=4
// R8: R3 core geometry (128^2 tile, BK=32, 3 LDS buffers, counted vmcnt)
// with 512 threads = 8 waves (wave-tile 32x64, acc[2][4]) -> 24 waves/CU
// (TLP x2 at identical memory structure). kv-role tiles interleaved
// every-5th for XCD balance. gemm_out same 8-wave core.

typedef unsigned short u16;
typedef __attribute__((ext_vector_type(8))) short bhalf8;   // 8 x bf16 (MFMA A/B frag)
typedef __attribute__((ext_vector_type(4))) float fvec4;    // MFMA C/D frag

#define MFMA(a, b, c) __builtin_amdgcn_mfma_f32_16x16x32_bf16((a), (b), (c), 0, 0, 0)

__device__ __forceinline__ u16 f2bf(float f) {
  unsigned u = __float_as_uint(f);
  u += 0x7fffu + ((u >> 16) & 1u);      // round-to-nearest-even
  return (u16)(u >> 16);
}
__device__ __forceinline__ float bf2f(u16 h) {
  return __uint_as_float(((unsigned)h) << 16);
}

// ---------------------------------------------------------------------------
// Fused preprocessing (unchanged from R3).
__global__ __launch_bounds__(256) void prep_kernel(
    const float* __restrict__ Wq, const float* __restrict__ Wkv,
    const float* __restrict__ Wo, u16* __restrict__ WqT,
    u16* __restrict__ WkvT, u16* __restrict__ WoT,
    const float* __restrict__ q, u16* __restrict__ qb,
    const float* __restrict__ kv, u16* __restrict__ kvb,
    float2* __restrict__ csT) {
  const int bid = blockIdx.x;
  if (bid < 4096) {
    __shared__ float tile[32][33];
    const float* W;
    u16* Wt;
    int N, t;
    if (bid < 1024)      { W = Wq;  Wt = WqT;  N = 1024; t = bid; }
    else if (bid < 3072) { W = Wkv; Wt = WkvT; N = 2048; t = bid - 1024; }
    else                 { W = Wo;  Wt = WoT;  N = 1024; t = bid - 3072; }
    const int sh = (N >> 11) + 5;               // 1024->5, 2048->6
    const int n0 = (t & ((1 << sh) - 1)) << 5;
    const int k0 = (t >> sh) << 5;
    const int tx = threadIdx.x & 31, ty = threadIdx.x >> 5;
#pragma unroll
    for (int i = 0; i < 32; i += 8)
      tile[ty + i][tx] = W[(size_t)(k0 + ty + i) * N + n0 + tx];
    __syncthreads();
#pragma unroll
    for (int i = 0; i < 32; i += 8)
      Wt[(size_t)(n0 + ty + i) * 1024 + k0 + tx] = f2bf(tile[tx][ty + i]);
    return;
  }
  const int NQ4 = 2097152, NKV4 = 262144, NR = 131072;
  const int stride = 2048 * 256;
  for (int u = (bid - 4096) * 256 + threadIdx.x; u < NQ4 + NKV4 + NR; u += stride) {
    if (u < NQ4) {
      const float4 v = ((const float4*)q)[u];
      ushort4 o;
      o.x = f2bf(v.x); o.y = f2bf(v.y); o.z = f2bf(v.z); o.w = f2bf(v.w);
      ((ushort4*)qb)[u] = o;
    } else if (u < NQ4 + NKV4) {
      const int i = u - NQ4;
      const float4 v = ((const float4*)kv)[i];
      ushort4 o;
      o.x = f2bf(v.x); o.y = f2bf(v.y); o.z = f2bf(v.z); o.w = f2bf(v.w);
      ((ushort4*)kvb)[i] = o;
    } else {
      const int i = u - NQ4 - NKV4;
      const int pos = i >> 5, j = i & 31;
      const float invf = expf(-(float)j * 0.28782313662425572f);  // ln(10000)/32
      float s, c;
      sincosf((float)pos * invf, &s, &c);
      csT[i] = make_float2(c, s);
    }
  }
}

// ---------------------------------------------------------------------------
// 128x128 GEMM tile core, 512 thr = 8 waves (4M x 2N), wave-tile 32x64 =
// acc[2][4] frags of 16x16 (mfma 16x16x32). BK=32, K=1024, 32 K-steps.
// 3 LDS buffers (16KB each, 48KB total -> 3 blocks/CU = 24 waves/CU).
// Stage 2 tiles ahead; each thread issues 1 A-chunk + 1 B-chunk (16B) per
// stage; steady s_waitcnt vmcnt(2) (= next tile's 2 loads landed).
// 16B-chunk XOR swizzle slot = g ^ ((row>>1)&3), same K-bijection both
// operands (MFMA contraction invariant). Hazard: STAGE(t+2) overwrites
// buf[(t-1)%3], whose ds_reads completed before the t-1 barrier.
__device__ __forceinline__ void gemm_core_8w(
    const u16* __restrict__ A, const u16* __restrict__ Bt,
    int m0, int n0, fvec4 acc[2][4], u16* As, u16* Bs) {
  const int tid = threadIdx.x;
  const int lane = tid & 63;
  const int wv = tid >> 6, wm = wv >> 1, wn = wv & 1;   // wm 0..3, wn 0..1

  int a_off[2], b_off[4];
#pragma unroll
  for (int i = 0; i < 2; ++i) {
    const int rA = wm * 32 + i * 16 + (lane & 15);
    a_off[i] = rA * 32 + (((lane >> 4) ^ ((rA >> 1) & 3)) << 3);
  }
#pragma unroll
  for (int i = 0; i < 4; ++i) {
    const int rB = wn * 64 + i * 16 + (lane & 15);
    b_off[i] = rB * 32 + (((lane >> 4) ^ ((rB >> 1) & 3)) << 3);
  }
  // staging: tile = 512 16B-chunks; thread tid stages chunk tid of A and B.
  const int rS = tid >> 2, gS = (tid & 3) ^ ((rS >> 1) & 3);
  const u16* ag = A + (size_t)(m0 + rS) * 1024 + gS * 8;
  const u16* bg = Bt + (size_t)(n0 + rS) * 1024 + gS * 8;
  const int ldst = tid * 8;

#define STAGE2(buf, kk)                                                      \
  do {                                                                       \
    __builtin_amdgcn_global_load_lds(                                        \
        (__attribute__((address_space(1))) void*)(ag + (kk)),                \
        (__attribute__((address_space(3))) void*)(As + (buf) * 4096 + ldst), \
        16, 0, 0);                                                           \
    __builtin_amdgcn_global_load_lds(                                        \
        (__attribute__((address_space(1))) void*)(bg + (kk)),                \
        (__attribute__((address_space(3))) void*)(Bs + (buf) * 4096 + ldst), \
        16, 0, 0);                                                           \
  } while (0)

  // prologue: stage tiles 0 and 1; wait tile 0 (vmcnt(2): oldest 2 done).
  STAGE2(0, 0);
  STAGE2(1, 32);
  asm volatile("s_waitcnt vmcnt(2)" ::: "memory");
  __builtin_amdgcn_s_barrier();

#pragma unroll
  for (int t = 0; t < 32; ++t) {
    const int k2 = t * 32 + 64;
    if (k2 < 1024) STAGE2((t + 2) % 3, k2);
    const int co = (t % 3) * 4096;
    bhalf8 af[2], bfv[4];
#pragma unroll
    for (int i = 0; i < 2; ++i) af[i] = *(const bhalf8*)(As + co + a_off[i]);
#pragma unroll
    for (int i = 0; i < 4; ++i) bfv[i] = *(const bhalf8*)(Bs + co + b_off[i]);
    __builtin_amdgcn_s_setprio(1);
#pragma unroll
    for (int mi = 0; mi < 2; ++mi)
#pragma unroll
      for (int ni = 0; ni < 4; ++ni)
        acc[mi][ni] = MFMA(af[mi], bfv[ni], acc[mi][ni]);
    __builtin_amdgcn_s_setprio(0);
    if (k2 < 1024) {
      asm volatile("s_waitcnt vmcnt(2)" ::: "memory");  // tile t+1 landed
    } else {
      asm volatile("s_waitcnt vmcnt(0)" ::: "memory");  // drain tail
    }
    __builtin_amdgcn_s_barrier();
  }
#undef STAGE2
}

#define GEMM_PROLOGUE()                                              \
  __shared__ __align__(16) u16 As[3 * 128 * 32];                     \
  __shared__ __align__(16) u16 Bs[3 * 128 * 32];                     \
  fvec4 acc[2][4];                                                   \
  _Pragma("unroll") for (int i = 0; i < 2; ++i)                      \
      _Pragma("unroll") for (int j = 0; j < 4; ++j)                  \
          acc[i][j] = (fvec4){0.f, 0.f, 0.f, 0.f};

// ---------------------------------------------------------------------------
// Fused GEMM1+GEMM2, 640 wgs x 512 thr (8 XCD chunks of 80; kv-role tiles
// interleaved as every 5th swz for per-XCD balance: 80 = 64 qh + 16 kv).
// qh role:  qh = bf16( RoPE(q @ Wq) * 0.125 )  M=8192 N=1024 (64x8 tiles)
// kv role:  kvl = kv @ Wkv (8x16 tiles); cols<1024 -> kh (RoPE), else vh
__global__ __launch_bounds__(512) void gemm12_kernel(
    const u16* __restrict__ qA, const u16* __restrict__ WqT,
    const u16* __restrict__ kvA, const u16* __restrict__ WkvT,
    u16* __restrict__ qh, u16* __restrict__ kh, u16* __restrict__ vh,
    const int* __restrict__ qpos, const int* __restrict__ kpos,
    const float2* __restrict__ csT) {
  GEMM_PROLOGUE();
  const int swz = ((blockIdx.x & 7) * 80) + (blockIdx.x >> 3);  // bijective, 640=8*80
  const int q5 = swz / 5, r5 = swz - q5 * 5;
  const bool isQ = (r5 < 4);
  const int lane = threadIdx.x & 63;
  const int wv = threadIdx.x >> 6, wm = wv >> 1, wn = wv & 1;

  const u16 *A, *Bt;
  int m0, n0;
  if (isQ) {
    const int id = q5 * 4 + r5;                    // 0..511
    A = qA; Bt = WqT;
    m0 = (id >> 3) * 128; n0 = (id & 7) * 128;
  } else {
    const int id = q5;                             // 0..127
    A = kvA; Bt = WkvT;
    m0 = (id >> 4) * 128; n0 = (id & 15) * 128;
  }
  gemm_core_8w(A, Bt, m0, n0, acc, As, Bs);

  if (isQ) {
#pragma unroll
    for (int mi = 0; mi < 2; ++mi) {
#pragma unroll
      for (int r = 0; r < 4; ++r) {
        const int rowg = m0 + wm * 32 + mi * 16 + (lane >> 4) * 4 + r;
        int pos = qpos[rowg];
        pos = pos < 0 ? 0 : (pos > 4095 ? 4095 : pos);
#pragma unroll
        for (int ni = 0; ni < 2; ++ni) {
          const int j = ni * 16 + (lane & 15);
          const float2 cs = csT[pos * 32 + j];
          const float x1 = acc[mi][ni][r], x2 = acc[mi][ni + 2][r];
          const int colg = n0 + wn * 64 + ni * 16 + (lane & 15);
          qh[(size_t)rowg * 1024 + colg]      = f2bf((x1 * cs.x - x2 * cs.y) * 0.125f);
          qh[(size_t)rowg * 1024 + colg + 32] = f2bf((x2 * cs.x + x1 * cs.y) * 0.125f);
        }
      }
    }
  } else {
    const bool isK = (n0 + wn * 64) < 1024;
#pragma unroll
    for (int mi = 0; mi < 2; ++mi) {
#pragma unroll
      for (int r = 0; r < 4; ++r) {
        const int rowg = m0 + wm * 32 + mi * 16 + (lane >> 4) * 4 + r;  // 0..1023
        if (isK) {
          int pos = kpos[rowg & 511];
          pos = pos < 0 ? 0 : (pos > 4095 ? 4095 : pos);
#pragma unroll
          for (int ni = 0; ni < 2; ++ni) {
            const int j = ni * 16 + (lane & 15);
            const float2 cs = csT[pos * 32 + j];
            const float x1 = acc[mi][ni][r], x2 = acc[mi][ni + 2][r];
            const int colg = n0 + wn * 64 + ni * 16 + (lane & 15);
            kh[(size_t)rowg * 1024 + colg]      = f2bf(x1 * cs.x - x2 * cs.y);
            kh[(size_t)rowg * 1024 + colg + 32] = f2bf(x2 * cs.x + x1 * cs.y);
          }
        } else {
#pragma unroll
          for (int ni = 0; ni < 4; ++ni) {
            const int colg = n0 + wn * 64 + ni * 16 + (lane & 15);
            vh[(size_t)rowg * 1024 + colg - 1024] = f2bf(acc[mi][ni][r]);
          }
        }
      }
    }
  }
}

// ---------------------------------------------------------------------------
// GEMM3: out_f32 = ctx @ Wo   M=8192 N=1024, 512 wgs x 512 thr
__global__ __launch_bounds__(512) void gemm_out_kernel(
    const u16* __restrict__ A, const u16* __restrict__ Bt,
    float* __restrict__ out) {
  GEMM_PROLOGUE();
  const int wg = ((blockIdx.x & 7) << 6) + (blockIdx.x >> 3);  // XCD swizzle, 512=8*64
  const int m0 = (wg >> 3) * 128, n0 = (wg & 7) * 128;
  gemm_core_8w(A, Bt, m0, n0, acc, As, Bs);
  const int lane = threadIdx.x & 63;
  const int wv = threadIdx.x >> 6, wm = wv >> 1, wn = wv & 1;
#pragma unroll
  for (int mi = 0; mi < 2; ++mi) {
#pragma unroll
    for (int r = 0; r < 4; ++r) {
      const int rowg = m0 + wm * 32 + mi * 16 + (lane >> 4) * 4 + r;
#pragma unroll
      for (int ni = 0; ni < 4; ++ni) {
        const int colg = n0 + wn * 64 + ni * 16 + (lane & 15);
        out[(size_t)rowg * 1024 + colg] = acc[mi][ni][r];
      }
    }
  }
}

// ---------------------------------------------------------------------------
// Sparse attention (unchanged): k in [max(seg-4,0), seg] (<=5 keys).
__global__ __launch_bounds__(256) void attn_kernel(
    const u16* __restrict__ qh, const u16* __restrict__ kh,
    const u16* __restrict__ vh, const int* __restrict__ seg_id,
    u16* __restrict__ ctx) {
  const int lane = threadIdx.x & 63;
  const int row = (blockIdx.x * 256 + threadIdx.x) >> 6;   // 0..8191
  const int b = row >> 12;
  const int sg = seg_id[row];
  const int kmin = sg > 4 ? sg - 4 : 0;

  const u16* qp = qh + (size_t)row * 1024 + lane * 16;
  const bhalf8 qa = *(const bhalf8*)qp;
  const bhalf8 qb = *(const bhalf8*)(qp + 8);
  float qv[16];
#pragma unroll
  for (int e = 0; e < 8; ++e) {
    qv[e] = bf2f((u16)qa[e]);
    qv[8 + e] = bf2f((u16)qb[e]);
  }

  float sc[5];
  float mx = -3.0e38f;
#pragma unroll
  for (int t = 0; t < 5; ++t) {
    const int k = kmin + t;                      // always in [0,511]
    const u16* kp = kh + (size_t)((b << 9) + k) * 1024 + lane * 16;
    const bhalf8 ka = *(const bhalf8*)kp;
    const bhalf8 kb = *(const bhalf8*)(kp + 8);
    float d = 0.f;
#pragma unroll
    for (int e = 0; e < 8; ++e)
      d += qv[e] * bf2f((u16)ka[e]) + qv[8 + e] * bf2f((u16)kb[e]);
    d += __shfl_xor(d, 1);
    d += __shfl_xor(d, 2);                       // sum over 4 lanes of this head
    sc[t] = (k <= sg) ? d : -3.0e38f;
    mx = fmaxf(mx, sc[t]);
  }

  float den = 0.f;
  float o[16];
#pragma unroll
  for (int e = 0; e < 16; ++e) o[e] = 0.f;
#pragma unroll
  for (int t = 0; t < 5; ++t) {
    const float p = __expf(sc[t] - mx);          // masked -> exp(-huge) = 0
    den += p;
    const int k = kmin + t;
    const u16* vp = vh + (size_t)((b << 9) + k) * 1024 + lane * 16;
    const bhalf8 va = *(const bhalf8*)vp;
    const bhalf8 vb = *(const bhalf8*)(vp + 8);
#pragma unroll
    for (int e = 0; e < 8; ++e) {
      o[e] += p * bf2f((u16)va[e]);
      o[8 + e] += p * bf2f((u16)vb[e]);
    }
  }
  const float inv = 1.f / den;
  bhalf8 oa, ob;
#pragma unroll
  for (int e = 0; e < 8; ++e) {
    oa[e] = (short)f2bf(o[e] * inv);
    ob[e] = (short)f2bf(o[8 + e] * inv);
  }
  u16* cp = ctx + (size_t)row * 1024 + lane * 16;
  *(bhalf8*)cp = oa;
  *(bhalf8*)(cp + 8) = ob;
}

// ---------------------------------------------------------------------------
extern "C" void kernel_launch(void* const* d_in, const int* in_sizes, int n_in,
                              void* d_out, int out_size, void* d_ws, size_t ws_size,
                              hipStream_t stream) {
  const float* q   = (const float*)d_in[0];
  const float* kv  = (const float*)d_in[1];
  const int* qpos  = (const int*)d_in[2];
  const int* kpos  = (const int*)d_in[3];
  const int* seg   = (const int*)d_in[4];
  const float* Wq  = (const float*)d_in[5];
  const float* Wkv = (const float*)d_in[6];
  const float* Wo  = (const float*)d_in[7];
  float* out = (float*)d_out;

  // workspace carve-up (~66 MB total)
  char* w = (char*)d_ws;
  u16* qb    = (u16*)w; w += (size_t)8192 * 1024 * 2;
  u16* kvb   = (u16*)w; w += (size_t)1024 * 1024 * 2;
  u16* WqT   = (u16*)w; w += (size_t)1024 * 1024 * 2;
  u16* WkvT  = (u16*)w; w += (size_t)2048 * 1024 * 2;
  u16* WoT   = (u16*)w; w += (size_t)1024 * 1024 * 2;
  u16* qhB   = (u16*)w; w += (size_t)8192 * 1024 * 2;
  u16* khB   = (u16*)w; w += (size_t)1024 * 1024 * 2;
  u16* vhB   = (u16*)w; w += (size_t)1024 * 1024 * 2;
  u16* ctxB  = (u16*)w; w += (size_t)8192 * 1024 * 2;
  float2* csT = (float2*)w; w += (size_t)4096 * 32 * 8;

  prep_kernel<<<6144, 256, 0, stream>>>(Wq, Wkv, Wo, WqT, WkvT, WoT,
                                        q, qb, kv, kvb, csT);
  gemm12_kernel<<<640, 512, 0, stream>>>(qb, WqT, kvb, WkvT,
                                         qhB, khB, vhB, qpos, kpos, csT);
  attn_kernel<<<2048, 256, 0, stream>>>(qhB, khB, vhB, seg, ctxB);
  gemm_out_kernel<<<512, 512, 0, stream>>>(ctxB, WoT, out);
}

// Round 9
// 92.598 us; speedup vs baseline: 1.5675x; 1.0054x over previous
//
#include <hip/hip_runtime.h>
#include <math.h>

// SegmentCausalCrossAttentionFlex on MI355X (gfx950)
// B=2, LQ=4096, LK=512, Q_DIM=KV_DIM=D_ATTN=1024, H=16, HD=64, LOOKBACK=4
// R9: R8 core (128^2 tile, BK=32, 3 LDS buffers, 512 thr = 8 waves,
// 24 waves/CU) with SINGLE barrier per K-step:
//   STAGE(t+2) -> ds_read(t) -> MFMA -> vmcnt(2) -> s_barrier.
// Proof of safety in comments at gemm_core_8w. Barriers halved 64 -> 33.

typedef unsigned short u16;
typedef __attribute__((ext_vector_type(8))) short bhalf8;   // 8 x bf16 (MFMA A/B frag)
typedef __attribute__((ext_vector_type(4))) float fvec4;    // MFMA C/D frag

#define MFMA(a, b, c) __builtin_amdgcn_mfma_f32_16x16x32_bf16((a), (b), (c), 0, 0, 0)

__device__ __forceinline__ u16 f2bf(float f) {
  unsigned u = __float_as_uint(f);
  u += 0x7fffu + ((u >> 16) & 1u);      // round-to-nearest-even
  return (u16)(u >> 16);
}
__device__ __forceinline__ float bf2f(u16 h) {
  return __uint_as_float(((unsigned)h) << 16);
}

// ---------------------------------------------------------------------------
// Fused preprocessing (unchanged from R3).
__global__ __launch_bounds__(256) void prep_kernel(
    const float* __restrict__ Wq, const float* __restrict__ Wkv,
    const float* __restrict__ Wo, u16* __restrict__ WqT,
    u16* __restrict__ WkvT, u16* __restrict__ WoT,
    const float* __restrict__ q, u16* __restrict__ qb,
    const float* __restrict__ kv, u16* __restrict__ kvb,
    float2* __restrict__ csT) {
  const int bid = blockIdx.x;
  if (bid < 4096) {
    __shared__ float tile[32][33];
    const float* W;
    u16* Wt;
    int N, t;
    if (bid < 1024)      { W = Wq;  Wt = WqT;  N = 1024; t = bid; }
    else if (bid < 3072) { W = Wkv; Wt = WkvT; N = 2048; t = bid - 1024; }
    else                 { W = Wo;  Wt = WoT;  N = 1024; t = bid - 3072; }
    const int sh = (N >> 11) + 5;               // 1024->5, 2048->6
    const int n0 = (t & ((1 << sh) - 1)) << 5;
    const int k0 = (t >> sh) << 5;
    const int tx = threadIdx.x & 31, ty = threadIdx.x >> 5;
#pragma unroll
    for (int i = 0; i < 32; i += 8)
      tile[ty + i][tx] = W[(size_t)(k0 + ty + i) * N + n0 + tx];
    __syncthreads();
#pragma unroll
    for (int i = 0; i < 32; i += 8)
      Wt[(size_t)(n0 + ty + i) * 1024 + k0 + tx] = f2bf(tile[tx][ty + i]);
    return;
  }
  const int NQ4 = 2097152, NKV4 = 262144, NR = 131072;
  const int stride = 2048 * 256;
  for (int u = (bid - 4096) * 256 + threadIdx.x; u < NQ4 + NKV4 + NR; u += stride) {
    if (u < NQ4) {
      const float4 v = ((const float4*)q)[u];
      ushort4 o;
      o.x = f2bf(v.x); o.y = f2bf(v.y); o.z = f2bf(v.z); o.w = f2bf(v.w);
      ((ushort4*)qb)[u] = o;
    } else if (u < NQ4 + NKV4) {
      const int i = u - NQ4;
      const float4 v = ((const float4*)kv)[i];
      ushort4 o;
      o.x = f2bf(v.x); o.y = f2bf(v.y); o.z = f2bf(v.z); o.w = f2bf(v.w);
      ((ushort4*)kvb)[i] = o;
    } else {
      const int i = u - NQ4 - NKV4;
      const int pos = i >> 5, j = i & 31;
      const float invf = expf(-(float)j * 0.28782313662425572f);  // ln(10000)/32
      float s, c;
      sincosf((float)pos * invf, &s, &c);
      csT[i] = make_float2(c, s);
    }
  }
}

// ---------------------------------------------------------------------------
// 128x128 GEMM tile core, 512 thr = 8 waves (4M x 2N), wave-tile 32x64 =
// acc[2][4] frags of 16x16 (mfma 16x16x32). BK=32, K=1024, 32 K-steps.
// 3 LDS buffers (48KB -> 3 blocks/CU = 24 waves/CU).
// SINGLE barrier per K-step. Safety proof:
//  (a) overwrite: STAGE(t+2) targets buf[(t+2)%3] == buf[(t-1)%3]; every
//      wave's ds_reads of that buffer (step t-1) were drained by the
//      compiler's lgkmcnt before its MFMAs, and the end-of-(t-1) barrier
//      orders them before any wave issues the step-t STAGE.
//  (b) readiness: each wave waits vmcnt(2) (its OWN 2 staged loads of tile
//      t+2 outstanding; its tile-t+1 loads complete) before the barrier,
//      so after the barrier tile t+1 is collectively fully in LDS.
//  (c) visibility of tile t to step-t ds_reads: established by the
//      end-of-(t-1) vmcnt+barrier.
// 16B-chunk XOR swizzle slot = g ^ ((row>>1)&3), same K-bijection both
// operands (MFMA contraction invariant).
__device__ __forceinline__ void gemm_core_8w(
    const u16* __restrict__ A, const u16* __restrict__ Bt,
    int m0, int n0, fvec4 acc[2][4], u16* As, u16* Bs) {
  const int tid = threadIdx.x;
  const int lane = tid & 63;
  const int wv = tid >> 6, wm = wv >> 1, wn = wv & 1;   // wm 0..3, wn 0..1

  int a_off[2], b_off[4];
#pragma unroll
  for (int i = 0; i < 2; ++i) {
    const int rA = wm * 32 + i * 16 + (lane & 15);
    a_off[i] = rA * 32 + (((lane >> 4) ^ ((rA >> 1) & 3)) << 3);
  }
#pragma unroll
  for (int i = 0; i < 4; ++i) {
    const int rB = wn * 64 + i * 16 + (lane & 15);
    b_off[i] = rB * 32 + (((lane >> 4) ^ ((rB >> 1) & 3)) << 3);
  }
  // staging: tile = 512 16B-chunks; thread tid stages chunk tid of A and B.
  const int rS = tid >> 2, gS = (tid & 3) ^ ((rS >> 1) & 3);
  const u16* ag = A + (size_t)(m0 + rS) * 1024 + gS * 8;
  const u16* bg = Bt + (size_t)(n0 + rS) * 1024 + gS * 8;
  const int ldst = tid * 8;

#define STAGE2(buf, kk)                                                      \
  do {                                                                       \
    __builtin_amdgcn_global_load_lds(                                        \
        (__attribute__((address_space(1))) void*)(ag + (kk)),                \
        (__attribute__((address_space(3))) void*)(As + (buf) * 4096 + ldst), \
        16, 0, 0);                                                           \
    __builtin_amdgcn_global_load_lds(                                        \
        (__attribute__((address_space(1))) void*)(bg + (kk)),                \
        (__attribute__((address_space(3))) void*)(Bs + (buf) * 4096 + ldst), \
        16, 0, 0);                                                           \
  } while (0)

  // prologue: stage tiles 0 and 1; wait tile 0 (vmcnt(2): oldest 2 done).
  STAGE2(0, 0);
  STAGE2(1, 32);
  asm volatile("s_waitcnt vmcnt(2)" ::: "memory");
  __builtin_amdgcn_s_barrier();

#pragma unroll
  for (int t = 0; t < 32; ++t) {
    const int k2 = t * 32 + 64;
    if (k2 < 1024) STAGE2((t + 2) % 3, k2);
    const int co = (t % 3) * 4096;
    bhalf8 af[2], bfv[4];
#pragma unroll
    for (int i = 0; i < 2; ++i) af[i] = *(const bhalf8*)(As + co + a_off[i]);
#pragma unroll
    for (int i = 0; i < 4; ++i) bfv[i] = *(const bhalf8*)(Bs + co + b_off[i]);
    __builtin_amdgcn_s_setprio(1);
#pragma unroll
    for (int mi = 0; mi < 2; ++mi)
#pragma unroll
      for (int ni = 0; ni < 4; ++ni)
        acc[mi][ni] = MFMA(af[mi], bfv[ni], acc[mi][ni]);
    __builtin_amdgcn_s_setprio(0);
    // single end-of-step sync (see proof above)
    if (t < 30) {
      asm volatile("s_waitcnt vmcnt(2)" ::: "memory");  // tile t+1 landed
      __builtin_amdgcn_s_barrier();
    } else if (t == 30) {
      asm volatile("s_waitcnt vmcnt(0)" ::: "memory");  // drain tail
      __builtin_amdgcn_s_barrier();
    }
    // t == 31: last step, epilogue reads only registers - no sync needed.
  }
#undef STAGE2
}

#define GEMM_PROLOGUE()                                              \
  __shared__ __align__(16) u16 As[3 * 128 * 32];                     \
  __shared__ __align__(16) u16 Bs[3 * 128 * 32];                     \
  fvec4 acc[2][4];                                                   \
  _Pragma("unroll") for (int i = 0; i < 2; ++i)                      \
      _Pragma("unroll") for (int j = 0; j < 4; ++j)                  \
          acc[i][j] = (fvec4){0.f, 0.f, 0.f, 0.f};

// ---------------------------------------------------------------------------
// Fused GEMM1+GEMM2, 640 wgs x 512 thr (8 XCD chunks of 80; kv-role tiles
// interleaved as every 5th swz for per-XCD balance: 80 = 64 qh + 16 kv).
// qh role:  qh = bf16( RoPE(q @ Wq) * 0.125 )  M=8192 N=1024 (64x8 tiles)
// kv role:  kvl = kv @ Wkv (8x16 tiles); cols<1024 -> kh (RoPE), else vh
__global__ __launch_bounds__(512) void gemm12_kernel(
    const u16* __restrict__ qA, const u16* __restrict__ WqT,
    const u16* __restrict__ kvA, const u16* __restrict__ WkvT,
    u16* __restrict__ qh, u16* __restrict__ kh, u16* __restrict__ vh,
    const int* __restrict__ qpos, const int* __restrict__ kpos,
    const float2* __restrict__ csT) {
  GEMM_PROLOGUE();
  const int swz = ((blockIdx.x & 7) * 80) + (blockIdx.x >> 3);  // bijective, 640=8*80
  const int q5 = swz / 5, r5 = swz - q5 * 5;
  const bool isQ = (r5 < 4);
  const int lane = threadIdx.x & 63;
  const int wv = threadIdx.x >> 6, wm = wv >> 1, wn = wv & 1;

  const u16 *A, *Bt;
  int m0, n0;
  if (isQ) {
    const int id = q5 * 4 + r5;                    // 0..511
    A = qA; Bt = WqT;
    m0 = (id >> 3) * 128; n0 = (id & 7) * 128;
  } else {
    const int id = q5;                             // 0..127
    A = kvA; Bt = WkvT;
    m0 = (id >> 4) * 128; n0 = (id & 15) * 128;
  }
  gemm_core_8w(A, Bt, m0, n0, acc, As, Bs);

  if (isQ) {
#pragma unroll
    for (int mi = 0; mi < 2; ++mi) {
#pragma unroll
      for (int r = 0; r < 4; ++r) {
        const int rowg = m0 + wm * 32 + mi * 16 + (lane >> 4) * 4 + r;
        int pos = qpos[rowg];
        pos = pos < 0 ? 0 : (pos > 4095 ? 4095 : pos);
#pragma unroll
        for (int ni = 0; ni < 2; ++ni) {
          const int j = ni * 16 + (lane & 15);
          const float2 cs = csT[pos * 32 + j];
          const float x1 = acc[mi][ni][r], x2 = acc[mi][ni + 2][r];
          const int colg = n0 + wn * 64 + ni * 16 + (lane & 15);
          qh[(size_t)rowg * 1024 + colg]      = f2bf((x1 * cs.x - x2 * cs.y) * 0.125f);
          qh[(size_t)rowg * 1024 + colg + 32] = f2bf((x2 * cs.x + x1 * cs.y) * 0.125f);
        }
      }
    }
  } else {
    const bool isK = (n0 + wn * 64) < 1024;
#pragma unroll
    for (int mi = 0; mi < 2; ++mi) {
#pragma unroll
      for (int r = 0; r < 4; ++r) {
        const int rowg = m0 + wm * 32 + mi * 16 + (lane >> 4) * 4 + r;  // 0..1023
        if (isK) {
          int pos = kpos[rowg & 511];
          pos = pos < 0 ? 0 : (pos > 4095 ? 4095 : pos);
#pragma unroll
          for (int ni = 0; ni < 2; ++ni) {
            const int j = ni * 16 + (lane & 15);
            const float2 cs = csT[pos * 32 + j];
            const float x1 = acc[mi][ni][r], x2 = acc[mi][ni + 2][r];
            const int colg = n0 + wn * 64 + ni * 16 + (lane & 15);
            kh[(size_t)rowg * 1024 + colg]      = f2bf(x1 * cs.x - x2 * cs.y);
            kh[(size_t)rowg * 1024 + colg + 32] = f2bf(x2 * cs.x + x1 * cs.y);
          }
        } else {
#pragma unroll
          for (int ni = 0; ni < 4; ++ni) {
            const int colg = n0 + wn * 64 + ni * 16 + (lane & 15);
            vh[(size_t)rowg * 1024 + colg - 1024] = f2bf(acc[mi][ni][r]);
          }
        }
      }
    }
  }
}

// ---------------------------------------------------------------------------
// GEMM3: out_f32 = ctx @ Wo   M=8192 N=1024, 512 wgs x 512 thr
__global__ __launch_bounds__(512) void gemm_out_kernel(
    const u16* __restrict__ A, const u16* __restrict__ Bt,
    float* __restrict__ out) {
  GEMM_PROLOGUE();
  const int wg = ((blockIdx.x & 7) << 6) + (blockIdx.x >> 3);  // XCD swizzle, 512=8*64
  const int m0 = (wg >> 3) * 128, n0 = (wg & 7) * 128;
  gemm_core_8w(A, Bt, m0, n0, acc, As, Bs);
  const int lane = threadIdx.x & 63;
  const int wv = threadIdx.x >> 6, wm = wv >> 1, wn = wv & 1;
#pragma unroll
  for (int mi = 0; mi < 2; ++mi) {
#pragma unroll
    for (int r = 0; r < 4; ++r) {
      const int rowg = m0 + wm * 32 + mi * 16 + (lane >> 4) * 4 + r;
#pragma unroll
      for (int ni = 0; ni < 4; ++ni) {
        const int colg = n0 + wn * 64 + ni * 16 + (lane & 15);
        out[(size_t)rowg * 1024 + colg] = acc[mi][ni][r];
      }
    }
  }
}

// ---------------------------------------------------------------------------
// Sparse attention (unchanged): k in [max(seg-4,0), seg] (<=5 keys).
__global__ __launch_bounds__(256) void attn_kernel(
    const u16* __restrict__ qh, const u16* __restrict__ kh,
    const u16* __restrict__ vh, const int* __restrict__ seg_id,
    u16* __restrict__ ctx) {
  const int lane = threadIdx.x & 63;
  const int row = (blockIdx.x * 256 + threadIdx.x) >> 6;   // 0..8191
  const int b = row >> 12;
  const int sg = seg_id[row];
  const int kmin = sg > 4 ? sg - 4 : 0;

  const u16* qp = qh + (size_t)row * 1024 + lane * 16;
  const bhalf8 qa = *(const bhalf8*)qp;
  const bhalf8 qb = *(const bhalf8*)(qp + 8);
  float qv[16];
#pragma unroll
  for (int e = 0; e < 8; ++e) {
    qv[e] = bf2f((u16)qa[e]);
    qv[8 + e] = bf2f((u16)qb[e]);
  }

  float sc[5];
  float mx = -3.0e38f;
#pragma unroll
  for (int t = 0; t < 5; ++t) {
    const int k = kmin + t;                      // always in [0,511]
    const u16* kp = kh + (size_t)((b << 9) + k) * 1024 + lane * 16;
    const bhalf8 ka = *(const bhalf8*)kp;
    const bhalf8 kb = *(const bhalf8*)(kp + 8);
    float d = 0.f;
#pragma unroll
    for (int e = 0; e < 8; ++e)
      d += qv[e] * bf2f((u16)ka[e]) + qv[8 + e] * bf2f((u16)kb[e]);
    d += __shfl_xor(d, 1);
    d += __shfl_xor(d, 2);                       // sum over 4 lanes of this head
    sc[t] = (k <= sg) ? d : -3.0e38f;
    mx = fmaxf(mx, sc[t]);
  }

  float den = 0.f;
  float o[16];
#pragma unroll
  for (int e = 0; e < 16; ++e) o[e] = 0.f;
#pragma unroll
  for (int t = 0; t < 5; ++t) {
    const float p = __expf(sc[t] - mx);          // masked -> exp(-huge) = 0
    den += p;
    const int k = kmin + t;
    const u16* vp = vh + (size_t)((b << 9) + k) * 1024 + lane * 16;
    const bhalf8 va = *(const bhalf8*)vp;
    const bhalf8 vb = *(const bhalf8*)(vp + 8);
#pragma unroll
    for (int e = 0; e < 8; ++e) {
      o[e] += p * bf2f((u16)va[e]);
      o[8 + e] += p * bf2f((u16)vb[e]);
    }
  }
  const float inv = 1.f / den;
  bhalf8 oa, ob;
#pragma unroll
  for (int e = 0; e < 8; ++e) {
    oa[e] = (short)f2bf(o[e] * inv);
    ob[e] = (short)f2bf(o[8 + e] * inv);
  }
  u16* cp = ctx + (size_t)row * 1024 + lane * 16;
  *(bhalf8*)cp = oa;
  *(bhalf8*)(cp + 8) = ob;
}

// ---------------------------------------------------------------------------
extern "C" void kernel_launch(void* const* d_in, const int* in_sizes, int n_in,
                              void* d_out, int out_size, void* d_ws, size_t ws_size,
                              hipStream_t stream) {
  const float* q   = (const float*)d_in[0];
  const float* kv  = (const float*)d_in[1];
  const int* qpos  = (const int*)d_in[2];
  const int* kpos  = (const int*)d_in[3];
  const int* seg   = (const int*)d_in[4];
  const float* Wq  = (const float*)d_in[5];
  const float* Wkv = (const float*)d_in[6];
  const float* Wo  = (const float*)d_in[7];
  float* out = (float*)d_out;

  // workspace carve-up (~66 MB total)
  char* w = (char*)d_ws;
  u16* qb    = (u16*)w; w += (size_t)8192 * 1024 * 2;
  u16* kvb   = (u16*)w; w += (size_t)1024 * 1024 * 2;
  u16* WqT   = (u16*)w; w += (size_t)1024 * 1024 * 2;
  u16* WkvT  = (u16*)w; w += (size_t)2048 * 1024 * 2;
  u16* WoT   = (u16*)w; w += (size_t)1024 * 1024 * 2;
  u16* qhB   = (u16*)w; w += (size_t)8192 * 1024 * 2;
  u16* khB   = (u16*)w; w += (size_t)1024 * 1024 * 2;
  u16* vhB   = (u16*)w; w += (size_t)1024 * 1024 * 2;
  u16* ctxB  = (u16*)w; w += (size_t)8192 * 1024 * 2;
  float2* csT = (float2*)w; w += (size_t)4096 * 32 * 8;

  prep_kernel<<<6144, 256, 0, stream>>>(Wq, Wkv, Wo, WqT, WkvT, WoT,
                                        q, qb, kv, kvb, csT);
  gemm12_kernel<<<640, 512, 0, stream>>>(qb, WqT, kvb, WkvT,
                                         qhB, khB, vhB, qpos, kpos, csT);
  attn_kernel<<<2048, 256, 0, stream>>>(qhB, khB, vhB, seg, ctxB);
  gemm_out_kernel<<<512, 512, 0, stream>>>(ctxB, WoT, out);
}